// Round 3
// baseline (1508.495 us; speedup 1.0000x reference)
//
#include <hip/hip_runtime.h>
#include <stdint.h>

typedef unsigned short ushort_t;
typedef __bf16 bf16x8 __attribute__((ext_vector_type(8)));
typedef float f32x4 __attribute__((ext_vector_type(4)));

#define D_MODEL 4096
#define SEQ 1024
#define BROWS 2048
#define QKV_N 6144
#define HD 128
#define FFN_PAD 10944
#define FFN_GRID 11008
#define ATTN_MULT 0.08838834764831845f

__device__ __forceinline__ unsigned short f2bf(float f){
  union { float f; unsigned u; } c; c.f = f;
  unsigned u = c.u + 0x7fffu + ((c.u >> 16) & 1u);
  return (unsigned short)(u >> 16);
}
__device__ __forceinline__ float bf2f(unsigned short h){
  union { unsigned u; float f; } c; c.u = ((unsigned)h) << 16;
  return c.f;
}
__device__ __forceinline__ f32x4 zero4(){ f32x4 z; z[0]=0.f; z[1]=0.f; z[2]=0.f; z[3]=0.f; return z; }
__device__ __forceinline__ bf16x8 ldb8(const void* p){ return *(const bf16x8*)p; }
__device__ __forceinline__ f32x4 MFMA(bf16x8 a, bf16x8 b, f32x4 c){
  return __builtin_amdgcn_mfma_f32_16x16x32_bf16(a, b, c, 0, 0, 0);
}
// async global->LDS, 16B per lane; LDS dest = wave-uniform base + lane*16
__device__ __forceinline__ void g2lds16(void* lds, const void* g){
  __builtin_amdgcn_global_load_lds(
      (const __attribute__((address_space(1))) void*)(uintptr_t)(g),
      (__attribute__((address_space(3))) void*)(uint32_t)(uintptr_t)(lds),
      16, 0, 0);
}
#define BAR() __builtin_amdgcn_s_barrier()
#define LGKM0() asm volatile("s_waitcnt lgkmcnt(0)" ::: "memory")
#define VMCNT2() asm volatile("s_waitcnt vmcnt(2)" ::: "memory")
#define PRIO1() __builtin_amdgcn_s_setprio(1)
#define PRIO0() __builtin_amdgcn_s_setprio(0)

// ---------------- RMSNorm (input) : hn = rms(x)*scale, bf16 out ----------------
__global__ __launch_bounds__(256) void rmsnorm_in(const float* __restrict__ x,
                                                  const float* __restrict__ sc,
                                                  ushort_t* __restrict__ out){
  int row = blockIdx.x, tid = threadIdx.x;
  const float4* xr = (const float4*)(x + (size_t)row*D_MODEL);
  float4 v[4]; float ss = 0.f;
#pragma unroll
  for (int i=0;i<4;i++){
    v[i] = xr[tid + i*256];
    ss += v[i].x*v[i].x + v[i].y*v[i].y + v[i].z*v[i].z + v[i].w*v[i].w;
  }
#pragma unroll
  for (int m=32;m;m>>=1) ss += __shfl_xor(ss, m);
  __shared__ float red[4];
  if ((tid&63)==0) red[tid>>6] = ss;
  __syncthreads();
  float inv = rsqrtf((red[0]+red[1]+red[2]+red[3])*(1.f/4096.f) + 1e-5f);
  const float4* scv = (const float4*)sc;
#pragma unroll
  for (int i=0;i<4;i++){
    float4 s4 = scv[tid + i*256];
    ushort4 o;
    o.x = f2bf(v[i].x*inv*s4.x); o.y = f2bf(v[i].y*inv*s4.y);
    o.z = f2bf(v[i].z*inv*s4.z); o.w = f2bf(v[i].w*inv*s4.w);
    ((ushort4*)out)[(size_t)row*1024 + tid + i*256] = o;
  }
}

// ---- residual+norm: h = base + rms(delta)*sc1 (fp32 out); opt hn2 = rms(h)*sc2 (bf16) ----
__global__ __launch_bounds__(256) void rmsnorm_resid(const float* __restrict__ base,
                                                     const float* __restrict__ delta,
                                                     const float* __restrict__ sc1,
                                                     float* __restrict__ hout,
                                                     const float* __restrict__ sc2,
                                                     ushort_t* __restrict__ hn2){
  int row = blockIdx.x, tid = threadIdx.x;
  const float4* dr = (const float4*)(delta + (size_t)row*D_MODEL);
  const float4* br = (const float4*)(base  + (size_t)row*D_MODEL);
  float4 d[4]; float ss = 0.f;
#pragma unroll
  for (int i=0;i<4;i++){
    d[i] = dr[tid + i*256];
    ss += d[i].x*d[i].x + d[i].y*d[i].y + d[i].z*d[i].z + d[i].w*d[i].w;
  }
#pragma unroll
  for (int m=32;m;m>>=1) ss += __shfl_xor(ss, m);
  __shared__ float red[4];
  if ((tid&63)==0) red[tid>>6] = ss;
  __syncthreads();
  float inv1 = rsqrtf((red[0]+red[1]+red[2]+red[3])*(1.f/4096.f) + 1e-5f);
  const float4* s1v = (const float4*)sc1;
  float4* ho = (float4*)(hout + (size_t)row*D_MODEL);
  float4 h4[4]; float ss2 = 0.f;
#pragma unroll
  for (int i=0;i<4;i++){
    float4 b4 = br[tid + i*256];
    float4 s4 = s1v[tid + i*256];
    float4 h;
    h.x = b4.x + d[i].x*inv1*s4.x;
    h.y = b4.y + d[i].y*inv1*s4.y;
    h.z = b4.z + d[i].z*inv1*s4.z;
    h.w = b4.w + d[i].w*inv1*s4.w;
    h4[i] = h;
    ho[tid + i*256] = h;
    ss2 += h.x*h.x + h.y*h.y + h.z*h.z + h.w*h.w;
  }
  if (sc2){
#pragma unroll
    for (int m=32;m;m>>=1) ss2 += __shfl_xor(ss2, m);
    __syncthreads();
    if ((tid&63)==0) red[tid>>6] = ss2;
    __syncthreads();
    float inv2 = rsqrtf((red[0]+red[1]+red[2]+red[3])*(1.f/4096.f) + 1e-5f);
    const float4* s2v = (const float4*)sc2;
#pragma unroll
    for (int i=0;i<4;i++){
      float4 s4 = s2v[tid + i*256];
      ushort4 o;
      o.x = f2bf(h4[i].x*inv2*s4.x); o.y = f2bf(h4[i].y*inv2*s4.y);
      o.z = f2bf(h4[i].z*inv2*s4.z); o.w = f2bf(h4[i].w*inv2*s4.w);
      ((ushort4*)hn2)[(size_t)row*1024 + tid + i*256] = o;
    }
  }
}

// ------- weight convert+transpose: WT[n][k] = (k<K && n<N) ? W[k][n] : 0, bf16 -------
__global__ __launch_bounds__(256) void convT(const float* __restrict__ W,
                                             ushort_t* __restrict__ WT,
                                             int K, int N, int Kp, int Np){
  __shared__ float tile[64][33];
  int n0 = blockIdx.x*32, k0 = blockIdx.y*64;
  int tx = threadIdx.x & 31, ty = threadIdx.x >> 5;   // ty in 0..7
#pragma unroll
  for (int i=0;i<8;i++){
    int k = k0 + ty + i*8, n = n0 + tx;
    tile[ty+i*8][tx] = (k < K && n < N) ? W[(size_t)k*N + n] : 0.f;
  }
  __syncthreads();
#pragma unroll
  for (int i=0;i<4;i++){
    int n = n0 + ty + i*8;
    if (n < Np){
      ushort2 o;
      o.x = f2bf(tile[tx*2  ][ty+i*8]);
      o.y = f2bf(tile[tx*2+1][ty+i*8]);
      *(ushort2*)&WT[(size_t)n*Kp + k0 + tx*2] = o;
    }
  }
}

// ============ 256x256 8-phase GEMM: C[M][N] = A[M][K] @ WT[N][K]^T (bf16) ============
// 512 threads (8 waves, 2M x 4N), BK=64, double-buffered 128KB LDS, raw barriers,
// counted vmcnt(2) once per K-tile (loads never drain to 0 in the loop).
// Staging ledger (slot = tile&1):  tile i+1 ch2..7 at phases 0..2, tile i+2 ch0,1 at
// phase 3 (into the slot just fully read; reads lgkm-drained before phase barrier).
// MODE 0: bf16 out; 1: fp32 out; 2: bf16, out[idx] = gelu(out[idx]) * acc
template<int MODE>
__global__ __launch_bounds__(512, 2) void gemm256(const ushort_t* __restrict__ A, int lda,
                                                  const ushort_t* __restrict__ WT, int ldw,
                                                  void* __restrict__ Cv, int ldc,
                                                  int Nvalid, int K){
  __shared__ __align__(16) char smem[131072];
  const int nwg = gridDim.x;
  const int lid = blockIdx.x;
  const int t  = (lid & 7) * (nwg >> 3) + (lid >> 3);   // bijective XCD chunking
  const int m0 = (t & 7) << 8, n0 = (t >> 3) << 8;      // m fastest (M=2048 -> 8 m-tiles)
  const int tid = threadIdx.x;
  const int w = tid >> 6, lane = tid & 63;
  const int wm = w >> 2, wn = w & 3;                    // wave tile: 128 x 64
  const int lo = lane & 15, hi = lane >> 4;
  const int srow = lane >> 3, scol = lane & 7;
  const int sw = scol ^ srow;                           // pre-swizzled source k-chunk
  const int rsw = lo & 7;
  const int NT = K >> 6;

  const ushort_t* pA = A  + (size_t)(m0 + w*8 + srow) * lda + sw*8;
  const ushort_t* pB = WT + (size_t)(n0 + w*8 + srow) * ldw + sw*8;

  // stage chunk c (0-3: A rows c*64.., 4-7: B rows (c-4)*64..) of K-tile tt
  auto stage = [&](int tt, int c){
    const ushort_t* g = (c < 4 ? pA + (size_t)(c*64)*lda : pB + (size_t)((c-4)*64)*ldw) + tt*64;
    char* l = smem + ((tt&1)<<16) + ((c>>2)<<15) + ((c&3)<<13) + (w<<10);
    g2lds16(l, g);
  };

  f32x4 acc[8][4];
#pragma unroll
  for (int i=0;i<8;i++)
#pragma unroll
    for (int j=0;j<4;j++) acc[i][j] = zero4();

  // prologue: tile0 fully, tile1 ch0,1  (outstanding = 10 per wave)
#pragma unroll
  for (int c=0;c<8;c++) stage(0, c);
  stage(1, 0); stage(1, 1);

  for (int i=0;i<NT;i++){
    VMCNT2();                       // all of tile i landed (newest 2 = tile i+1 ch0,1)
    BAR();
    const char* sA = smem + ((i&1)<<16);
    const char* sB = sA + 32768;
    const bool st1 = (i+1 < NT), st2 = (i+2 < NT);
    bf16x8 af[4][2], bfl[2][2], bfh[2][2];
    // ---- phase 0: A rows rf0-3 + B cf0-1 ; MFMA quad (r0,c0) ----
#pragma unroll
    for (int rf=0;rf<4;rf++)
#pragma unroll
      for (int kc=0;kc<2;kc++)
        af[rf][kc] = ldb8(sA + (wm*128 + rf*16 + lo)*128 + (((kc*4+hi)^rsw)<<4));
#pragma unroll
    for (int cf=0;cf<2;cf++)
#pragma unroll
      for (int kc=0;kc<2;kc++)
        bfl[cf][kc] = ldb8(sB + (wn*64 + cf*16 + lo)*128 + (((kc*4+hi)^rsw)<<4));
    if (st1){ stage(i+1, 2); stage(i+1, 3); }
    BAR(); LGKM0(); PRIO1();
#pragma unroll
    for (int rf=0;rf<4;rf++)
#pragma unroll
      for (int cf=0;cf<2;cf++)
#pragma unroll
        for (int kc=0;kc<2;kc++)
          acc[rf][cf] = MFMA(af[rf][kc], bfl[cf][kc], acc[rf][cf]);
    PRIO0(); BAR();
    // ---- phase 1: B cf2-3 ; MFMA quad (r0,c1) ----
#pragma unroll
    for (int cf=0;cf<2;cf++)
#pragma unroll
      for (int kc=0;kc<2;kc++)
        bfh[cf][kc] = ldb8(sB + (wn*64 + (cf+2)*16 + lo)*128 + (((kc*4+hi)^rsw)<<4));
    if (st1){ stage(i+1, 4); stage(i+1, 5); }
    BAR(); LGKM0(); PRIO1();
#pragma unroll
    for (int rf=0;rf<4;rf++)
#pragma unroll
      for (int cf=0;cf<2;cf++)
#pragma unroll
        for (int kc=0;kc<2;kc++)
          acc[rf][cf+2] = MFMA(af[rf][kc], bfh[cf][kc], acc[rf][cf+2]);
    PRIO0(); BAR();
    // ---- phase 2: A rows rf4-7 ; MFMA quad (r1,c0) ----
#pragma unroll
    for (int rf=0;rf<4;rf++)
#pragma unroll
      for (int kc=0;kc<2;kc++)
        af[rf][kc] = ldb8(sA + (wm*128 + 64 + rf*16 + lo)*128 + (((kc*4+hi)^rsw)<<4));
    if (st1){ stage(i+1, 6); stage(i+1, 7); }
    BAR(); LGKM0(); PRIO1();
#pragma unroll
    for (int rf=0;rf<4;rf++)
#pragma unroll
      for (int cf=0;cf<2;cf++)
#pragma unroll
        for (int kc=0;kc<2;kc++)
          acc[4+rf][cf] = MFMA(af[rf][kc], bfl[cf][kc], acc[4+rf][cf]);
    PRIO0(); BAR();
    // ---- phase 3: MFMA quad (r1,c1) ; stage tile i+2 ch0,1 into this slot ----
    if (st2){ stage(i+2, 0); stage(i+2, 1); }
    BAR(); PRIO1();
#pragma unroll
    for (int rf=0;rf<4;rf++)
#pragma unroll
      for (int cf=0;cf<2;cf++)
#pragma unroll
        for (int kc=0;kc<2;kc++)
          acc[4+rf][cf+2] = MFMA(af[rf][kc], bfh[cf][kc], acc[4+rf][cf+2]);
    PRIO0(); BAR();
  }
  // epilogue
#pragma unroll
  for (int rf=0;rf<8;rf++){
#pragma unroll
    for (int cf=0;cf<4;cf++){
#pragma unroll
      for (int r=0;r<4;r++){
        int m = m0 + wm*128 + rf*16 + hi*4 + r;
        int n = n0 + wn*64 + cf*16 + lo;
        if (n < Nvalid){
          float v = acc[rf][cf][r];
          size_t idx = (size_t)m*ldc + n;
          if (MODE == 1){
            ((float*)Cv)[idx] = v;
          } else if (MODE == 0){
            ((ushort_t*)Cv)[idx] = f2bf(v);
          } else {
            float g = bf2f(((ushort_t*)Cv)[idx]);
            float ga = 0.5f*g*(1.f + tanhf(0.7978845608028654f*(g + 0.044715f*g*g*g)));
            ((ushort_t*)Cv)[idx] = f2bf(ga * v);
          }
        }
      }
    }
  }
}

// ---------------- RoPE ----------------
__global__ void rope_tab_kernel(float* __restrict__ tab){
  int s = blockIdx.x, i = threadIdx.x;             // s<1024, i<64
  float invf = __expf(-(float)i * (9.210340371976184f/64.f));  // 10000^(-i/64)
  float ph = (float)s * invf;
  float sn, cs;
  sincosf(ph, &sn, &cs);
  tab[s*128 + i] = cs;
  tab[s*128 + 64 + i] = sn;
}

__global__ __launch_bounds__(256) void rope_apply(ushort_t* __restrict__ qkv,
                                                  const float* __restrict__ tab){
  int idx = blockIdx.x*256 + threadIdx.x;          // 2048*40*64 total
  int pr = idx & 63;
  int h  = (idx >> 6) % 40;                        // 32 q heads + 8 k heads
  int row = idx / 2560;
  int t = row & (SEQ-1);
  ushort_t* p = qkv + (size_t)row*QKV_N + h*HD + pr;
  float c = tab[t*128 + pr], s = tab[t*128 + 64 + pr];
  float x1 = bf2f(p[0]), x2 = bf2f(p[64]);
  p[0]  = f2bf(x1*c - x2*s);
  p[64] = f2bf(x2*c + x1*s);
}

// ---------------- V transpose: VT[d][m] = qkv[m][5120+d] ----------------
__global__ __launch_bounds__(256) void transpose_v(const ushort_t* __restrict__ qkv,
                                                   ushort_t* __restrict__ VT){
  __shared__ ushort_t tile[32][33];
  int d0 = blockIdx.x*32, m0 = blockIdx.y*32;
  int tx = threadIdx.x & 31, ty = threadIdx.x >> 5;
#pragma unroll
  for (int i=0;i<4;i++)
    tile[ty + i*8][tx] = qkv[(size_t)(m0 + ty + i*8)*QKV_N + 5120 + d0 + tx];
  __syncthreads();
#pragma unroll
  for (int i=0;i<4;i++)
    VT[(size_t)(d0 + ty + i*8)*BROWS + m0 + tx] = tile[tx][ty + i*8];
}

// ---------------- Flash attention with tanh soft-cap, GQA, causal ----------------
__global__ __launch_bounds__(256) void attn_kernel(const ushort_t* __restrict__ qkv,
                                                   const ushort_t* __restrict__ VT,
                                                   ushort_t* __restrict__ outp){
  const int blk = blockIdx.x;
  const int bh = blk & 63;
  const int tgrp = 15 - (blk >> 6);     // heavy tiles dispatched first
  const int b = bh >> 5, qh = bh & 31, kv = qh >> 2;
  const int w = threadIdx.x >> 6, lane = threadIdx.x & 63;
  const int lo = lane & 15, hi = lane >> 4;
  const int t0 = tgrp*64 + w*16;
  __shared__ ushort_t P[4][16][72];     // per-wave P transpose buffer
  ushort_t (*Pw)[72] = P[w];

  const ushort_t* Qb = qkv + (size_t)(b*SEQ + t0 + lo)*QKV_N + qh*HD + hi*8;
  bf16x8 qf[4];
#pragma unroll
  for (int c=0;c<4;c++) qf[c] = ldb8(Qb + c*32);

  f32x4 of[8];
#pragma unroll
  for (int i=0;i<8;i++) of[i] = zero4();
  float ls[4] = {0.f,0.f,0.f,0.f};

  const ushort_t* Kb = qkv + (size_t)(b*SEQ + lo)*QKV_N + D_MODEL + kv*HD + hi*8;
  const ushort_t* Vb = VT + (size_t)(kv*HD + lo)*BROWS + b*SEQ + hi*8;

  const int nst = tgrp + 1;
  for (int st=0; st<nst; st++){
    const int s0 = st*64;
    f32x4 sacc[4];
#pragma unroll
    for (int nf=0;nf<4;nf++) sacc[nf] = zero4();
#pragma unroll
    for (int c=0;c<4;c++){
#pragma unroll
      for (int nf=0;nf<4;nf++){
        bf16x8 kf = ldb8(Kb + (size_t)(s0 + nf*16)*QKV_N + c*32);
        sacc[nf] = MFMA(qf[c], kf, sacc[nf]);
      }
    }
    // softmax (fixed max = 30 thanks to tanh cap) + write P^T to LDS
#pragma unroll
    for (int nf=0;nf<4;nf++){
#pragma unroll
      for (int r=0;r<4;r++){
        int tq = t0 + hi*4 + r;
        int s = s0 + nf*16 + lo;
        float xx = sacc[nf][r] * ATTN_MULT;
        float z = fminf(fmaxf(xx*(2.f/30.f), -80.f), 80.f);
        float e = __expf(z);
        float th = (e - 1.f)/(e + 1.f);
        float p = (s <= tq) ? __expf(30.f*th - 30.f) : 0.f;
        ls[r] += p;
        Pw[hi*4+r][nf*16+lo] = f2bf(p);
      }
    }
    __builtin_amdgcn_sched_barrier(0);
    __builtin_amdgcn_s_waitcnt(0xc07f);   // lgkmcnt(0): P writes visible wave-wide
    __builtin_amdgcn_sched_barrier(0);
#pragma unroll
    for (int c2=0;c2<2;c2++){
      bf16x8 pf = ldb8(&Pw[lo][c2*32 + hi*8]);
#pragma unroll
      for (int nf2=0;nf2<8;nf2++){
        bf16x8 vf = ldb8(Vb + (size_t)(nf2*16)*BROWS + s0 + c2*32);
        of[nf2] = MFMA(pf, vf, of[nf2]);
      }
    }
    __builtin_amdgcn_sched_barrier(0);
  }
#pragma unroll
  for (int m=1;m<16;m<<=1){
#pragma unroll
    for (int r=0;r<4;r++) ls[r] += __shfl_xor(ls[r], m);
  }
  float inv[4];
#pragma unroll
  for (int r=0;r<4;r++) inv[r] = 1.f/ls[r];
  ushort_t* Ob = outp + (size_t)(b*SEQ + t0 + hi*4)*D_MODEL + qh*HD + lo;
#pragma unroll
  for (int nf2=0;nf2<8;nf2++)
#pragma unroll
    for (int r=0;r<4;r++)
      Ob[(size_t)r*D_MODEL + nf2*16] = f2bf(of[nf2][r]*inv[r]);
}

// =============================== host launcher ===============================
extern "C" void kernel_launch(void* const* d_in, const int* in_sizes, int n_in,
                              void* d_out, int out_size, void* d_ws, size_t ws_size,
                              hipStream_t stream){
  const float* x        = (const float*)d_in[0];
  const float* sc_pre_a = (const float*)d_in[2];
  const float* sc_post_a= (const float*)d_in[3];
  const float* sc_pre_m = (const float*)d_in[4];
  const float* sc_post_m= (const float*)d_in[5];
  const float* wq  = (const float*)d_in[6];
  const float* wk  = (const float*)d_in[7];
  const float* wv  = (const float*)d_in[8];
  const float* wo  = (const float*)d_in[9];
  const float* wg  = (const float*)d_in[10];
  const float* wva = (const float*)d_in[11];
  const float* wou = (const float*)d_in[12];

  char* ws = (char*)d_ws;
  size_t off = 0;
  auto alloc = [&](size_t bytes)->void*{
    void* p = ws + off; off += (bytes + 255) & ~(size_t)255; return p;
  };
  ushort_t* WT   = (ushort_t*)alloc((size_t)FFN_GRID*D_MODEL*2); // reusable weight slot
  ushort_t* hn   = (ushort_t*)alloc((size_t)BROWS*D_MODEL*2);
  ushort_t* qkv  = (ushort_t*)alloc((size_t)BROWS*QKV_N*2);
  ushort_t* VT   = (ushort_t*)alloc((size_t)SEQ*BROWS*2);
  ushort_t* attn = (ushort_t*)alloc((size_t)BROWS*D_MODEL*2);
  float*    tmp32= (float*)alloc((size_t)BROWS*D_MODEL*4);
  ushort_t* hn2  = (ushort_t*)alloc((size_t)BROWS*D_MODEL*2);
  ushort_t* act  = (ushort_t*)alloc((size_t)BROWS*FFN_PAD*2);
  float*    rtab = (float*)alloc((size_t)SEQ*128*4);
  float* h = (float*)d_out;

  // 1. pre-attn norm
  rmsnorm_in<<<BROWS, 256, 0, stream>>>(x, sc_pre_a, hn);
  // 2. convert wq|wk|wv -> WT[6144][4096]
  convT<<<dim3(4096/32, 4096/64), 256, 0, stream>>>(wq, WT,                     4096, 4096, 4096, 4096);
  convT<<<dim3(1024/32, 4096/64), 256, 0, stream>>>(wk, WT + (size_t)4096*4096, 4096, 1024, 4096, 1024);
  convT<<<dim3(1024/32, 4096/64), 256, 0, stream>>>(wv, WT + (size_t)5120*4096, 4096, 1024, 4096, 1024);
  // 3. fused QKV GEMM (24 n-tiles x 8 m-tiles)
  gemm256<0><<<192, 512, 0, stream>>>(hn, 4096, WT, 4096, qkv, QKV_N, QKV_N, 4096);
  // 4. RoPE on q,k
  rope_tab_kernel<<<SEQ, 64, 0, stream>>>(rtab);
  rope_apply<<<(BROWS*40*64)/256, 256, 0, stream>>>(qkv, rtab);
  // 5. V transpose for PV B-operand
  transpose_v<<<dim3(32,64), 256, 0, stream>>>(qkv, VT);
  // 6. attention
  attn_kernel<<<1024, 256, 0, stream>>>(qkv, VT, attn);
  // 7-8. O projection
  convT<<<dim3(4096/32, 4096/64), 256, 0, stream>>>(wo, WT, 4096, 4096, 4096, 4096);
  gemm256<1><<<128, 512, 0, stream>>>(attn, 4096, WT, 4096, tmp32, 4096, 4096, 4096);
  // 9. h = x + rms(o)*sc ; hn2 = rms(h)*sc_pre_mlp
  rmsnorm_resid<<<BROWS, 256, 0, stream>>>(x, tmp32, sc_post_a, h, sc_pre_m, hn2);
  // 10-11. gate GEMM (43 n-tiles x 8 m-tiles)
  convT<<<dim3(FFN_GRID/32, 4096/64), 256, 0, stream>>>(wg, WT, 4096, 10928, 4096, FFN_GRID);
  gemm256<0><<<344, 512, 0, stream>>>(hn2, 4096, WT, 4096, act, FFN_PAD, FFN_PAD, 4096);
  // 12-13. val GEMM fused with act = gelu(gate)*val
  convT<<<dim3(FFN_GRID/32, 4096/64), 256, 0, stream>>>(wva, WT, 4096, 10928, 4096, FFN_GRID);
  gemm256<2><<<344, 512, 0, stream>>>(hn2, 4096, WT, 4096, act, FFN_PAD, FFN_PAD, 4096);
  // 14-15. out projection (K padded 10928->10944 with zeros)
  convT<<<dim3(4096/32, FFN_PAD/64), 256, 0, stream>>>(wou, WT, 10928, 4096, FFN_PAD, 4096);
  gemm256<1><<<128, 512, 0, stream>>>(act, FFN_PAD, WT, FFN_PAD, tmp32, 4096, 4096, FFN_PAD);
  // 16. final residual + norm (in-place on d_out)
  rmsnorm_resid<<<BROWS, 256, 0, stream>>>(h, tmp32, sc_post_m, h, nullptr, nullptr);
}

// Round 4
// 1316.487 us; speedup vs baseline: 1.1458x; 1.1458x over previous
//
#include <hip/hip_runtime.h>
#include <stdint.h>

typedef unsigned short ushort_t;
typedef __bf16 bf16x8 __attribute__((ext_vector_type(8)));
typedef float f32x4 __attribute__((ext_vector_type(4)));

#define D_MODEL 4096
#define SEQ 1024
#define BROWS 2048
#define QKV_N 6144
#define HD 128
#define FFN_PAD 10944
#define FFN_GRID 11008
#define ATTN_MULT 0.08838834764831845f

__device__ __forceinline__ unsigned short f2bf(float f){
  union { float f; unsigned u; } c; c.f = f;
  unsigned u = c.u + 0x7fffu + ((c.u >> 16) & 1u);
  return (unsigned short)(u >> 16);
}
__device__ __forceinline__ float bf2f(unsigned short h){
  union { unsigned u; float f; } c; c.u = ((unsigned)h) << 16;
  return c.f;
}
__device__ __forceinline__ f32x4 zero4(){ f32x4 z; z[0]=0.f; z[1]=0.f; z[2]=0.f; z[3]=0.f; return z; }
__device__ __forceinline__ bf16x8 ldb8(const void* p){ return *(const bf16x8*)p; }
__device__ __forceinline__ f32x4 MFMA(bf16x8 a, bf16x8 b, f32x4 c){
  return __builtin_amdgcn_mfma_f32_16x16x32_bf16(a, b, c, 0, 0, 0);
}
// async global->LDS, 16B per lane; LDS dest = wave-uniform base + lane*16
__device__ __forceinline__ void g2lds16(void* lds, const void* g){
  __builtin_amdgcn_global_load_lds(
      (const __attribute__((address_space(1))) void*)(uintptr_t)(g),
      (__attribute__((address_space(3))) void*)(uint32_t)(uintptr_t)(lds),
      16, 0, 0);
}
#define BAR() __builtin_amdgcn_s_barrier()
#define VMCNT6() asm volatile("s_waitcnt vmcnt(6)" ::: "memory")
#define VMCNT0() asm volatile("s_waitcnt vmcnt(0)" ::: "memory")
#define PRIO1() __builtin_amdgcn_s_setprio(1)
#define PRIO0() __builtin_amdgcn_s_setprio(0)

// ---------------- RMSNorm (input) : hn = rms(x)*scale, bf16 out ----------------
__global__ __launch_bounds__(256) void rmsnorm_in(const float* __restrict__ x,
                                                  const float* __restrict__ sc,
                                                  ushort_t* __restrict__ out){
  int row = blockIdx.x, tid = threadIdx.x;
  const float4* xr = (const float4*)(x + (size_t)row*D_MODEL);
  float4 v[4]; float ss = 0.f;
#pragma unroll
  for (int i=0;i<4;i++){
    v[i] = xr[tid + i*256];
    ss += v[i].x*v[i].x + v[i].y*v[i].y + v[i].z*v[i].z + v[i].w*v[i].w;
  }
#pragma unroll
  for (int m=32;m;m>>=1) ss += __shfl_xor(ss, m);
  __shared__ float red[4];
  if ((tid&63)==0) red[tid>>6] = ss;
  __syncthreads();
  float inv = rsqrtf((red[0]+red[1]+red[2]+red[3])*(1.f/4096.f) + 1e-5f);
  const float4* scv = (const float4*)sc;
#pragma unroll
  for (int i=0;i<4;i++){
    float4 s4 = scv[tid + i*256];
    ushort4 o;
    o.x = f2bf(v[i].x*inv*s4.x); o.y = f2bf(v[i].y*inv*s4.y);
    o.z = f2bf(v[i].z*inv*s4.z); o.w = f2bf(v[i].w*inv*s4.w);
    ((ushort4*)out)[(size_t)row*1024 + tid + i*256] = o;
  }
}

// ---- residual+norm: h = base + rms(delta)*sc1 (fp32 out); opt hn2 = rms(h)*sc2 (bf16) ----
__global__ __launch_bounds__(256) void rmsnorm_resid(const float* __restrict__ base,
                                                     const float* __restrict__ delta,
                                                     const float* __restrict__ sc1,
                                                     float* __restrict__ hout,
                                                     const float* __restrict__ sc2,
                                                     ushort_t* __restrict__ hn2){
  int row = blockIdx.x, tid = threadIdx.x;
  const float4* dr = (const float4*)(delta + (size_t)row*D_MODEL);
  const float4* br = (const float4*)(base  + (size_t)row*D_MODEL);
  float4 d[4]; float ss = 0.f;
#pragma unroll
  for (int i=0;i<4;i++){
    d[i] = dr[tid + i*256];
    ss += d[i].x*d[i].x + d[i].y*d[i].y + d[i].z*d[i].z + d[i].w*d[i].w;
  }
#pragma unroll
  for (int m=32;m;m>>=1) ss += __shfl_xor(ss, m);
  __shared__ float red[4];
  if ((tid&63)==0) red[tid>>6] = ss;
  __syncthreads();
  float inv1 = rsqrtf((red[0]+red[1]+red[2]+red[3])*(1.f/4096.f) + 1e-5f);
  const float4* s1v = (const float4*)sc1;
  float4* ho = (float4*)(hout + (size_t)row*D_MODEL);
  float4 h4[4]; float ss2 = 0.f;
#pragma unroll
  for (int i=0;i<4;i++){
    float4 b4 = br[tid + i*256];
    float4 s4 = s1v[tid + i*256];
    float4 h;
    h.x = b4.x + d[i].x*inv1*s4.x;
    h.y = b4.y + d[i].y*inv1*s4.y;
    h.z = b4.z + d[i].z*inv1*s4.z;
    h.w = b4.w + d[i].w*inv1*s4.w;
    h4[i] = h;
    ho[tid + i*256] = h;
    ss2 += h.x*h.x + h.y*h.y + h.z*h.z + h.w*h.w;
  }
  if (sc2){
#pragma unroll
    for (int m=32;m;m>>=1) ss2 += __shfl_xor(ss2, m);
    __syncthreads();
    if ((tid&63)==0) red[tid>>6] = ss2;
    __syncthreads();
    float inv2 = rsqrtf((red[0]+red[1]+red[2]+red[3])*(1.f/4096.f) + 1e-5f);
    const float4* s2v = (const float4*)sc2;
#pragma unroll
    for (int i=0;i<4;i++){
      float4 s4 = s2v[tid + i*256];
      ushort4 o;
      o.x = f2bf(h4[i].x*inv2*s4.x); o.y = f2bf(h4[i].y*inv2*s4.y);
      o.z = f2bf(h4[i].z*inv2*s4.z); o.w = f2bf(h4[i].w*inv2*s4.w);
      ((ushort4*)hn2)[(size_t)row*1024 + tid + i*256] = o;
    }
  }
}

// ------- weight convert+transpose: WT[n][k] = (k<K && n<N) ? W[k][n] : 0, bf16 -------
__global__ __launch_bounds__(256) void convT(const float* __restrict__ W,
                                             ushort_t* __restrict__ WT,
                                             int K, int N, int Kp, int Np){
  __shared__ float tile[64][33];
  int n0 = blockIdx.x*32, k0 = blockIdx.y*64;
  int tx = threadIdx.x & 31, ty = threadIdx.x >> 5;   // ty in 0..7
#pragma unroll
  for (int i=0;i<8;i++){
    int k = k0 + ty + i*8, n = n0 + tx;
    tile[ty+i*8][tx] = (k < K && n < N) ? W[(size_t)k*N + n] : 0.f;
  }
  __syncthreads();
#pragma unroll
  for (int i=0;i<4;i++){
    int n = n0 + ty + i*8;
    if (n < Np){
      ushort2 o;
      o.x = f2bf(tile[tx*2  ][ty+i*8]);
      o.y = f2bf(tile[tx*2+1][ty+i*8]);
      *(ushort2*)&WT[(size_t)n*Kp + k0 + tx*2] = o;
    }
  }
}

// ======== 256x128 triple-buffered GEMM: C[M][N] = A[M][K] @ WT[N][K]^T (bf16) ========
// 512 threads (8 waves, 4M x 2N, wave tile 64x64), BK=64, LDS = 3 slots x 48KB.
// Ledger: during tile i we stage tile i+2 into slot (i+2)%3 (last read at tile i-1 ->
// no race); use-distance >= 4 phases. vmcnt(6) at tile start waits only on loads
// issued >= 2 K-tiles ago (the 6 in flight = tile i+1's); vmcnt(0) at the final tile.
// MODE 0: bf16 out; 1: fp32 out; 2: bf16, out[idx] = gelu(out[idx]) * acc
template<int MODE>
__global__ __launch_bounds__(512, 2) void gemm256(const ushort_t* __restrict__ A, int lda,
                                                  const ushort_t* __restrict__ WT, int ldw,
                                                  void* __restrict__ Cv, int ldc,
                                                  int Nvalid, int K){
  __shared__ __align__(16) char smem[147456];           // 3 x 48KB
  const int nwg = gridDim.x;
  const int lid = blockIdx.x;
  const int t  = (lid & 7) * (nwg >> 3) + (lid >> 3);   // bijective XCD chunking
  const int m0 = (t & 7) << 8;                          // BM=256 (M=2048 -> 8 m-tiles)
  const int n0 = (t >> 3) << 7;                         // BN=128, m fastest
  const int tid = threadIdx.x;
  const int w = tid >> 6, lane = tid & 63;
  const int wm = w >> 1, wn = w & 1;                    // wave tile 64(M) x 64(N)
  const int lo = lane & 15, hi = lane >> 4;
  const int srow = lane >> 3, scol = lane & 7;
  const int sw = scol ^ srow;                           // pre-swizzled source k-chunk
  const int rsw = lo & 7;
  const int NT = K >> 6;

  const ushort_t* pA = A  + (size_t)(m0 + w*8 + srow) * lda + sw*8;
  const ushort_t* pB = WT + (size_t)(n0 + w*8 + srow) * ldw + sw*8;

  // stage chunk c of K-tile tt into slot: c 0-3 = A rows c*64.., c 4-5 = B rows (c-4)*64..
  auto stage = [&](int tt, int slot, int c){
    const ushort_t* g = (c < 4 ? pA + (size_t)(c*64)*lda : pB + (size_t)((c-4)*64)*ldw) + tt*64;
    char* l = smem + slot*49152 + (c < 4 ? c*8192 : 32768 + (c-4)*8192) + (w<<10);
    g2lds16(l, g);
  };

  f32x4 acc[4][4];
#pragma unroll
  for (int i=0;i<4;i++)
#pragma unroll
    for (int j=0;j<4;j++) acc[i][j] = zero4();

  // prologue: tiles 0,1 fully staged (12 loads/thread outstanding)
#pragma unroll
  for (int c=0;c<6;c++) stage(0, 0, c);
#pragma unroll
  for (int c=0;c<6;c++) stage(1, 1, c);

  int cur = 0;
  for (int i=0;i<NT;i++){
    if (i == NT-1) VMCNT0(); else VMCNT6();   // tile i fully landed
    BAR();
    const char* sA = smem + cur*49152;
    const char* sB = sA + 32768;
    const int nxt = (cur == 2) ? 0 : cur + 1;
    const int nn  = (nxt == 2) ? 0 : nxt + 1;           // slot for tile i+2
    const bool st2 = (i+2 < NT);
    bf16x8 af[4][2], bfr[4][2];
    // ---- phase A: frags A rf0-3 + B cf0-1 ; stage 3 chunks ; MFMA half (cf0-1) ----
#pragma unroll
    for (int rf=0;rf<4;rf++)
#pragma unroll
      for (int kc=0;kc<2;kc++)
        af[rf][kc] = ldb8(sA + (wm*64 + rf*16 + lo)*128 + (((kc*4+hi)^rsw)<<4));
#pragma unroll
    for (int cf=0;cf<2;cf++)
#pragma unroll
      for (int kc=0;kc<2;kc++)
        bfr[cf][kc] = ldb8(sB + (wn*64 + cf*16 + lo)*128 + (((kc*4+hi)^rsw)<<4));
    if (st2){ stage(i+2, nn, 0); stage(i+2, nn, 1); stage(i+2, nn, 2); }
    BAR(); PRIO1();
#pragma unroll
    for (int rf=0;rf<4;rf++)
#pragma unroll
      for (int cf=0;cf<2;cf++)
#pragma unroll
        for (int kc=0;kc<2;kc++)
          acc[rf][cf] = MFMA(af[rf][kc], bfr[cf][kc], acc[rf][cf]);
    PRIO0(); BAR();
    // ---- phase B: frags B cf2-3 ; stage 3 chunks ; MFMA half (cf2-3) ----
#pragma unroll
    for (int cf=2;cf<4;cf++)
#pragma unroll
      for (int kc=0;kc<2;kc++)
        bfr[cf][kc] = ldb8(sB + (wn*64 + cf*16 + lo)*128 + (((kc*4+hi)^rsw)<<4));
    if (st2){ stage(i+2, nn, 3); stage(i+2, nn, 4); stage(i+2, nn, 5); }
    BAR(); PRIO1();
#pragma unroll
    for (int rf=0;rf<4;rf++)
#pragma unroll
      for (int cf=2;cf<4;cf++)
#pragma unroll
        for (int kc=0;kc<2;kc++)
          acc[rf][cf] = MFMA(af[rf][kc], bfr[cf][kc], acc[rf][cf]);
    PRIO0(); BAR();
    cur = nxt;
  }
  // epilogue
#pragma unroll
  for (int rf=0;rf<4;rf++){
#pragma unroll
    for (int cf=0;cf<4;cf++){
#pragma unroll
      for (int r=0;r<4;r++){
        int m = m0 + wm*64 + rf*16 + hi*4 + r;
        int n = n0 + wn*64 + cf*16 + lo;
        if (n < Nvalid){
          float v = acc[rf][cf][r];
          size_t idx = (size_t)m*ldc + n;
          if (MODE == 1){
            ((float*)Cv)[idx] = v;
          } else if (MODE == 0){
            ((ushort_t*)Cv)[idx] = f2bf(v);
          } else {
            float g = bf2f(((ushort_t*)Cv)[idx]);
            float ga = 0.5f*g*(1.f + tanhf(0.7978845608028654f*(g + 0.044715f*g*g*g)));
            ((ushort_t*)Cv)[idx] = f2bf(ga * v);
          }
        }
      }
    }
  }
}

// ---------------- RoPE ----------------
__global__ void rope_tab_kernel(float* __restrict__ tab){
  int s = blockIdx.x, i = threadIdx.x;             // s<1024, i<64
  float invf = __expf(-(float)i * (9.210340371976184f/64.f));  // 10000^(-i/64)
  float ph = (float)s * invf;
  float sn, cs;
  sincosf(ph, &sn, &cs);
  tab[s*128 + i] = cs;
  tab[s*128 + 64 + i] = sn;
}

__global__ __launch_bounds__(256) void rope_apply(ushort_t* __restrict__ qkv,
                                                  const float* __restrict__ tab){
  int idx = blockIdx.x*256 + threadIdx.x;          // 2048*40*64 total
  int pr = idx & 63;
  int h  = (idx >> 6) % 40;                        // 32 q heads + 8 k heads
  int row = idx / 2560;
  int t = row & (SEQ-1);
  ushort_t* p = qkv + (size_t)row*QKV_N + h*HD + pr;
  float c = tab[t*128 + pr], s = tab[t*128 + 64 + pr];
  float x1 = bf2f(p[0]), x2 = bf2f(p[64]);
  p[0]  = f2bf(x1*c - x2*s);
  p[64] = f2bf(x2*c + x1*s);
}

// ---------------- V transpose: VT[d][m] = qkv[m][5120+d] ----------------
__global__ __launch_bounds__(256) void transpose_v(const ushort_t* __restrict__ qkv,
                                                   ushort_t* __restrict__ VT){
  __shared__ ushort_t tile[32][33];
  int d0 = blockIdx.x*32, m0 = blockIdx.y*32;
  int tx = threadIdx.x & 31, ty = threadIdx.x >> 5;
#pragma unroll
  for (int i=0;i<4;i++)
    tile[ty + i*8][tx] = qkv[(size_t)(m0 + ty + i*8)*QKV_N + 5120 + d0 + tx];
  __syncthreads();
#pragma unroll
  for (int i=0;i<4;i++)
    VT[(size_t)(d0 + ty + i*8)*BROWS + m0 + tx] = tile[tx][ty + i*8];
}

// ---------------- Flash attention with tanh soft-cap, GQA, causal ----------------
__global__ __launch_bounds__(256) void attn_kernel(const ushort_t* __restrict__ qkv,
                                                   const ushort_t* __restrict__ VT,
                                                   ushort_t* __restrict__ outp){
  const int blk = blockIdx.x;
  const int bh = blk & 63;
  const int tgrp = 15 - (blk >> 6);     // heavy tiles dispatched first
  const int b = bh >> 5, qh = bh & 31, kv = qh >> 2;
  const int w = threadIdx.x >> 6, lane = threadIdx.x & 63;
  const int lo = lane & 15, hi = lane >> 4;
  const int t0 = tgrp*64 + w*16;
  __shared__ ushort_t P[4][16][72];     // per-wave P transpose buffer
  ushort_t (*Pw)[72] = P[w];

  const ushort_t* Qb = qkv + (size_t)(b*SEQ + t0 + lo)*QKV_N + qh*HD + hi*8;
  bf16x8 qf[4];
#pragma unroll
  for (int c=0;c<4;c++) qf[c] = ldb8(Qb + c*32);

  f32x4 of[8];
#pragma unroll
  for (int i=0;i<8;i++) of[i] = zero4();
  float ls[4] = {0.f,0.f,0.f,0.f};

  const ushort_t* Kb = qkv + (size_t)(b*SEQ + lo)*QKV_N + D_MODEL + kv*HD + hi*8;
  const ushort_t* Vb = VT + (size_t)(kv*HD + lo)*BROWS + b*SEQ + hi*8;

  const int nst = tgrp + 1;
  for (int st=0; st<nst; st++){
    const int s0 = st*64;
    f32x4 sacc[4];
#pragma unroll
    for (int nf=0;nf<4;nf++) sacc[nf] = zero4();
#pragma unroll
    for (int c=0;c<4;c++){
#pragma unroll
      for (int nf=0;nf<4;nf++){
        bf16x8 kf = ldb8(Kb + (size_t)(s0 + nf*16)*QKV_N + c*32);
        sacc[nf] = MFMA(qf[c], kf, sacc[nf]);
      }
    }
    // softmax (fixed max = 30 thanks to tanh cap) + write P^T to LDS
#pragma unroll
    for (int nf=0;nf<4;nf++){
#pragma unroll
      for (int r=0;r<4;r++){
        int tq = t0 + hi*4 + r;
        int s = s0 + nf*16 + lo;
        float xx = sacc[nf][r] * ATTN_MULT;
        float z = fminf(fmaxf(xx*(2.f/30.f), -80.f), 80.f);
        float e = __expf(z);
        float th = (e - 1.f)/(e + 1.f);
        float p = (s <= tq) ? __expf(30.f*th - 30.f) : 0.f;
        ls[r] += p;
        Pw[hi*4+r][nf*16+lo] = f2bf(p);
      }
    }
    __builtin_amdgcn_sched_barrier(0);
    __builtin_amdgcn_s_waitcnt(0xc07f);   // lgkmcnt(0): P writes visible wave-wide
    __builtin_amdgcn_sched_barrier(0);
#pragma unroll
    for (int c2=0;c2<2;c2++){
      bf16x8 pf = ldb8(&Pw[lo][c2*32 + hi*8]);
#pragma unroll
      for (int nf2=0;nf2<8;nf2++){
        bf16x8 vf = ldb8(Vb + (size_t)(nf2*16)*BROWS + s0 + c2*32);
        of[nf2] = MFMA(pf, vf, of[nf2]);
      }
    }
    __builtin_amdgcn_sched_barrier(0);
  }
#pragma unroll
  for (int m=1;m<16;m<<=1){
#pragma unroll
    for (int r=0;r<4;r++) ls[r] += __shfl_xor(ls[r], m);
  }
  float inv[4];
#pragma unroll
  for (int r=0;r<4;r++) inv[r] = 1.f/ls[r];
  ushort_t* Ob = outp + (size_t)(b*SEQ + t0 + hi*4)*D_MODEL + qh*HD + lo;
#pragma unroll
  for (int nf2=0;nf2<8;nf2++)
#pragma unroll
    for (int r=0;r<4;r++)
      Ob[(size_t)r*D_MODEL + nf2*16] = f2bf(of[nf2][r]*inv[r]);
}

// =============================== host launcher ===============================
extern "C" void kernel_launch(void* const* d_in, const int* in_sizes, int n_in,
                              void* d_out, int out_size, void* d_ws, size_t ws_size,
                              hipStream_t stream){
  const float* x        = (const float*)d_in[0];
  const float* sc_pre_a = (const float*)d_in[2];
  const float* sc_post_a= (const float*)d_in[3];
  const float* sc_pre_m = (const float*)d_in[4];
  const float* sc_post_m= (const float*)d_in[5];
  const float* wq  = (const float*)d_in[6];
  const float* wk  = (const float*)d_in[7];
  const float* wv  = (const float*)d_in[8];
  const float* wo  = (const float*)d_in[9];
  const float* wg  = (const float*)d_in[10];
  const float* wva = (const float*)d_in[11];
  const float* wou = (const float*)d_in[12];

  char* ws = (char*)d_ws;
  size_t off = 0;
  auto alloc = [&](size_t bytes)->void*{
    void* p = ws + off; off += (bytes + 255) & ~(size_t)255; return p;
  };
  ushort_t* WT   = (ushort_t*)alloc((size_t)FFN_GRID*D_MODEL*2); // reusable weight slot
  ushort_t* hn   = (ushort_t*)alloc((size_t)BROWS*D_MODEL*2);
  ushort_t* qkv  = (ushort_t*)alloc((size_t)BROWS*QKV_N*2);
  ushort_t* VT   = (ushort_t*)alloc((size_t)SEQ*BROWS*2);
  ushort_t* attn = (ushort_t*)alloc((size_t)BROWS*D_MODEL*2);
  float*    tmp32= (float*)alloc((size_t)BROWS*D_MODEL*4);
  ushort_t* hn2  = (ushort_t*)alloc((size_t)BROWS*D_MODEL*2);
  ushort_t* act  = (ushort_t*)alloc((size_t)BROWS*FFN_PAD*2);
  float*    rtab = (float*)alloc((size_t)SEQ*128*4);
  float* h = (float*)d_out;

  // 1. pre-attn norm
  rmsnorm_in<<<BROWS, 256, 0, stream>>>(x, sc_pre_a, hn);
  // 2. convert wq|wk|wv -> WT[6144][4096]
  convT<<<dim3(4096/32, 4096/64), 256, 0, stream>>>(wq, WT,                     4096, 4096, 4096, 4096);
  convT<<<dim3(1024/32, 4096/64), 256, 0, stream>>>(wk, WT + (size_t)4096*4096, 4096, 1024, 4096, 1024);
  convT<<<dim3(1024/32, 4096/64), 256, 0, stream>>>(wv, WT + (size_t)5120*4096, 4096, 1024, 4096, 1024);
  // 3. fused QKV GEMM (8 m x 48 n = 384 blocks)
  gemm256<0><<<384, 512, 0, stream>>>(hn, 4096, WT, 4096, qkv, QKV_N, QKV_N, 4096);
  // 4. RoPE on q,k
  rope_tab_kernel<<<SEQ, 64, 0, stream>>>(rtab);
  rope_apply<<<(BROWS*40*64)/256, 256, 0, stream>>>(qkv, rtab);
  // 5. V transpose for PV B-operand
  transpose_v<<<dim3(32,64), 256, 0, stream>>>(qkv, VT);
  // 6. attention
  attn_kernel<<<1024, 256, 0, stream>>>(qkv, VT, attn);
  // 7-8. O projection (8 x 32 = 256 blocks, 100% fill)
  convT<<<dim3(4096/32, 4096/64), 256, 0, stream>>>(wo, WT, 4096, 4096, 4096, 4096);
  gemm256<1><<<256, 512, 0, stream>>>(attn, 4096, WT, 4096, tmp32, 4096, 4096, 4096);
  // 9. h = x + rms(o)*sc ; hn2 = rms(h)*sc_pre_mlp
  rmsnorm_resid<<<BROWS, 256, 0, stream>>>(x, tmp32, sc_post_a, h, sc_pre_m, hn2);
  // 10-11. gate GEMM (8 x 86 = 688 blocks)
  convT<<<dim3(FFN_GRID/32, 4096/64), 256, 0, stream>>>(wg, WT, 4096, 10928, 4096, FFN_GRID);
  gemm256<0><<<688, 512, 0, stream>>>(hn2, 4096, WT, 4096, act, FFN_PAD, FFN_PAD, 4096);
  // 12-13. val GEMM fused with act = gelu(gate)*val
  convT<<<dim3(FFN_GRID/32, 4096/64), 256, 0, stream>>>(wva, WT, 4096, 10928, 4096, FFN_GRID);
  gemm256<2><<<688, 512, 0, stream>>>(hn2, 4096, WT, 4096, act, FFN_PAD, FFN_PAD, 4096);
  // 14-15. out projection (K padded 10928->10944 with zeros; 256 blocks, 100% fill)
  convT<<<dim3(4096/32, FFN_PAD/64), 256, 0, stream>>>(wou, WT, 10928, 4096, FFN_PAD, 4096);
  gemm256<1><<<256, 512, 0, stream>>>(act, FFN_PAD, WT, FFN_PAD, tmp32, 4096, 4096, FFN_PAD);
  // 16. final residual + norm (in-place on d_out)
  rmsnorm_resid<<<BROWS, 256, 0, stream>>>(h, tmp32, sc_post_m, h, nullptr, nullptr);
}

// Round 5
// 1281.658 us; speedup vs baseline: 1.1770x; 1.0272x over previous
//
#include <hip/hip_runtime.h>
#include <stdint.h>

typedef unsigned short ushort_t;
typedef __bf16 bf16x8 __attribute__((ext_vector_type(8)));
typedef float f32x4 __attribute__((ext_vector_type(4)));

#define D_MODEL 4096
#define SEQ 1024
#define BROWS 2048
#define QKV_N 6144
#define HD 128
#define FFN_PAD 10944
#define FFN_GRID 11008
#define ATTN_MULT 0.08838834764831845f

__device__ __forceinline__ unsigned short f2bf(float f){
  union { float f; unsigned u; } c; c.f = f;
  unsigned u = c.u + 0x7fffu + ((c.u >> 16) & 1u);
  return (unsigned short)(u >> 16);
}
__device__ __forceinline__ float bf2f(unsigned short h){
  union { unsigned u; float f; } c; c.u = ((unsigned)h) << 16;
  return c.f;
}
__device__ __forceinline__ f32x4 zero4(){ f32x4 z; z[0]=0.f; z[1]=0.f; z[2]=0.f; z[3]=0.f; return z; }
__device__ __forceinline__ bf16x8 ldb8(const void* p){ return *(const bf16x8*)p; }
__device__ __forceinline__ f32x4 MFMA(bf16x8 a, bf16x8 b, f32x4 c){
  return __builtin_amdgcn_mfma_f32_16x16x32_bf16(a, b, c, 0, 0, 0);
}
// async global->LDS, 16B per lane; LDS dest = wave-uniform base + lane*16
__device__ __forceinline__ void g2lds16(void* lds, const void* g){
  __builtin_amdgcn_global_load_lds(
      (const __attribute__((address_space(1))) void*)(uintptr_t)(g),
      (__attribute__((address_space(3))) void*)(uint32_t)(uintptr_t)(lds),
      16, 0, 0);
}
#define BAR() __builtin_amdgcn_s_barrier()
#define VMCNT6() asm volatile("s_waitcnt vmcnt(6)" ::: "memory")
#define VMCNT0() asm volatile("s_waitcnt vmcnt(0)" ::: "memory")

// ---------------- RMSNorm (input) : hn = rms(x)*scale, bf16 out ----------------
__global__ __launch_bounds__(256) void rmsnorm_in(const float* __restrict__ x,
                                                  const float* __restrict__ sc,
                                                  ushort_t* __restrict__ out){
  int row = blockIdx.x, tid = threadIdx.x;
  const float4* xr = (const float4*)(x + (size_t)row*D_MODEL);
  float4 v[4]; float ss = 0.f;
#pragma unroll
  for (int i=0;i<4;i++){
    v[i] = xr[tid + i*256];
    ss += v[i].x*v[i].x + v[i].y*v[i].y + v[i].z*v[i].z + v[i].w*v[i].w;
  }
#pragma unroll
  for (int m=32;m;m>>=1) ss += __shfl_xor(ss, m);
  __shared__ float red[4];
  if ((tid&63)==0) red[tid>>6] = ss;
  __syncthreads();
  float inv = rsqrtf((red[0]+red[1]+red[2]+red[3])*(1.f/4096.f) + 1e-5f);
  const float4* scv = (const float4*)sc;
#pragma unroll
  for (int i=0;i<4;i++){
    float4 s4 = scv[tid + i*256];
    ushort4 o;
    o.x = f2bf(v[i].x*inv*s4.x); o.y = f2bf(v[i].y*inv*s4.y);
    o.z = f2bf(v[i].z*inv*s4.z); o.w = f2bf(v[i].w*inv*s4.w);
    ((ushort4*)out)[(size_t)row*1024 + tid + i*256] = o;
  }
}

// ---- residual+norm: h = base + rms(delta)*sc1 (fp32 out); opt hn2 = rms(h)*sc2 (bf16) ----
__global__ __launch_bounds__(256) void rmsnorm_resid(const float* __restrict__ base,
                                                     const float* __restrict__ delta,
                                                     const float* __restrict__ sc1,
                                                     float* __restrict__ hout,
                                                     const float* __restrict__ sc2,
                                                     ushort_t* __restrict__ hn2){
  int row = blockIdx.x, tid = threadIdx.x;
  const float4* dr = (const float4*)(delta + (size_t)row*D_MODEL);
  const float4* br = (const float4*)(base  + (size_t)row*D_MODEL);
  float4 d[4]; float ss = 0.f;
#pragma unroll
  for (int i=0;i<4;i++){
    d[i] = dr[tid + i*256];
    ss += d[i].x*d[i].x + d[i].y*d[i].y + d[i].z*d[i].z + d[i].w*d[i].w;
  }
#pragma unroll
  for (int m=32;m;m>>=1) ss += __shfl_xor(ss, m);
  __shared__ float red[4];
  if ((tid&63)==0) red[tid>>6] = ss;
  __syncthreads();
  float inv1 = rsqrtf((red[0]+red[1]+red[2]+red[3])*(1.f/4096.f) + 1e-5f);
  const float4* s1v = (const float4*)sc1;
  float4* ho = (float4*)(hout + (size_t)row*D_MODEL);
  float4 h4[4]; float ss2 = 0.f;
#pragma unroll
  for (int i=0;i<4;i++){
    float4 b4 = br[tid + i*256];
    float4 s4 = s1v[tid + i*256];
    float4 h;
    h.x = b4.x + d[i].x*inv1*s4.x;
    h.y = b4.y + d[i].y*inv1*s4.y;
    h.z = b4.z + d[i].z*inv1*s4.z;
    h.w = b4.w + d[i].w*inv1*s4.w;
    h4[i] = h;
    ho[tid + i*256] = h;
    ss2 += h.x*h.x + h.y*h.y + h.z*h.z + h.w*h.w;
  }
  if (sc2){
#pragma unroll
    for (int m=32;m;m>>=1) ss2 += __shfl_xor(ss2, m);
    __syncthreads();
    if ((tid&63)==0) red[tid>>6] = ss2;
    __syncthreads();
    float inv2 = rsqrtf((red[0]+red[1]+red[2]+red[3])*(1.f/4096.f) + 1e-5f);
    const float4* s2v = (const float4*)sc2;
#pragma unroll
    for (int i=0;i<4;i++){
      float4 s4 = s2v[tid + i*256];
      ushort4 o;
      o.x = f2bf(h4[i].x*inv2*s4.x); o.y = f2bf(h4[i].y*inv2*s4.y);
      o.z = f2bf(h4[i].z*inv2*s4.z); o.w = f2bf(h4[i].w*inv2*s4.w);
      ((ushort4*)hn2)[(size_t)row*1024 + tid + i*256] = o;
    }
  }
}

// ------- weight convert+transpose: WT[n][k] = (k<K && n<N) ? W[k][n] : 0, bf16 -------
__global__ __launch_bounds__(256) void convT(const float* __restrict__ W,
                                             ushort_t* __restrict__ WT,
                                             int K, int N, int Kp, int Np){
  __shared__ float tile[64][33];
  int n0 = blockIdx.x*32, k0 = blockIdx.y*64;
  int tx = threadIdx.x & 31, ty = threadIdx.x >> 5;   // ty in 0..7
#pragma unroll
  for (int i=0;i<8;i++){
    int k = k0 + ty + i*8, n = n0 + tx;
    tile[ty+i*8][tx] = (k < K && n < N) ? W[(size_t)k*N + n] : 0.f;
  }
  __syncthreads();
#pragma unroll
  for (int i=0;i<4;i++){
    int n = n0 + ty + i*8;
    if (n < Np){
      ushort2 o;
      o.x = f2bf(tile[tx*2  ][ty+i*8]);
      o.y = f2bf(tile[tx*2+1][ty+i*8]);
      *(ushort2*)&WT[(size_t)n*Kp + k0 + tx*2] = o;
    }
  }
}

// ======== 256x128 triple-buffered GEMM: C[M][N] = A[M][K] @ WT[N][K]^T (bf16) ========
// 512 threads (8 waves, 4M x 2N, wave tile 64x64), BK=64, LDS = 3 slots x 48KB.
// ONE barrier per K-tile. During tile i: stage tile i+2 into slot (i+2)%3 (slot was
// last READ at tile i-1; every frag read of tile i-1 is consumed by an MFMA before
// the tile-i barrier, so the barrier alone orders read->write). Frag ds_reads and 32
// MFMAs are compiler-scheduled (counted lgkmcnt interleave, m97 evidence) so LDS time
// hides under MFMA. vmcnt(6) at tile start = tile i fully landed (6 in flight = tile
// i+1's); vmcnt(0) only at the final tile. Loads never drain to 0 mid-loop.
// MODE 0: bf16 out; 1: fp32 out; 2: bf16, out[idx] = gelu(out[idx]) * acc
template<int MODE>
__global__ __launch_bounds__(512, 2) void gemm256(const ushort_t* __restrict__ A, int lda,
                                                  const ushort_t* __restrict__ WT, int ldw,
                                                  void* __restrict__ Cv, int ldc,
                                                  int Nvalid, int K){
  __shared__ __align__(16) char smem[147456];           // 3 x 48KB
  const int nwg = gridDim.x;
  const int lid = blockIdx.x;
  const int t  = (lid & 7) * (nwg >> 3) + (lid >> 3);   // bijective XCD chunking
  const int m0 = (t & 7) << 8;                          // BM=256 (M=2048 -> 8 m-tiles)
  const int n0 = (t >> 3) << 7;                         // BN=128, m fastest
  const int tid = threadIdx.x;
  const int w = tid >> 6, lane = tid & 63;
  const int wm = w >> 1, wn = w & 1;                    // wave tile 64(M) x 64(N)
  const int lo = lane & 15, hi = lane >> 4;
  const int srow = lane >> 3, scol = lane & 7;
  const int sw = scol ^ srow;                           // pre-swizzled source k-chunk
  const int rsw = lo & 7;
  const int NT = K >> 6;

  const ushort_t* pA = A  + (size_t)(m0 + w*8 + srow) * lda + sw*8;
  const ushort_t* pB = WT + (size_t)(n0 + w*8 + srow) * ldw + sw*8;

  // stage chunk c of K-tile tt into slot: c 0-3 = A rows c*64.., c 4-5 = B rows (c-4)*64..
  auto stage = [&](int tt, int slot, int c){
    const ushort_t* g = (c < 4 ? pA + (size_t)(c*64)*lda : pB + (size_t)((c-4)*64)*ldw) + tt*64;
    char* l = smem + slot*49152 + (c < 4 ? c*8192 : 32768 + (c-4)*8192) + (w<<10);
    g2lds16(l, g);
  };

  f32x4 acc[4][4];
#pragma unroll
  for (int i=0;i<4;i++)
#pragma unroll
    for (int j=0;j<4;j++) acc[i][j] = zero4();

  // prologue: tiles 0,1 fully staged (12 loads/thread outstanding)
#pragma unroll
  for (int c=0;c<6;c++) stage(0, 0, c);
#pragma unroll
  for (int c=0;c<6;c++) stage(1, 1, c);

  int cur = 0;
  for (int i=0;i<NT;i++){
    if (i == NT-1) VMCNT0(); else VMCNT6();   // tile i fully landed
    BAR();
    const char* sA = smem + cur*49152;
    const char* sB = sA + 32768;
    const int nxt = (cur == 2) ? 0 : cur + 1;
    const int nn  = (nxt == 2) ? 0 : nxt + 1;           // slot for tile i+2
    if (i+2 < NT){
      stage(i+2, nn, 0); stage(i+2, nn, 1); stage(i+2, nn, 2);
      stage(i+2, nn, 3); stage(i+2, nn, 4); stage(i+2, nn, 5);
    }
    // frag reads + MFMAs: no internal barriers, compiler interleaves via counted lgkmcnt
    bf16x8 af[4][2], bfr[4][2];
#pragma unroll
    for (int rf=0;rf<4;rf++)
#pragma unroll
      for (int kc=0;kc<2;kc++)
        af[rf][kc] = ldb8(sA + (wm*64 + rf*16 + lo)*128 + (((kc*4+hi)^rsw)<<4));
#pragma unroll
    for (int cf=0;cf<4;cf++)
#pragma unroll
      for (int kc=0;kc<2;kc++)
        bfr[cf][kc] = ldb8(sB + (wn*64 + cf*16 + lo)*128 + (((kc*4+hi)^rsw)<<4));
#pragma unroll
    for (int rf=0;rf<4;rf++)
#pragma unroll
      for (int cf=0;cf<4;cf++)
#pragma unroll
        for (int kc=0;kc<2;kc++)
          acc[rf][cf] = MFMA(af[rf][kc], bfr[cf][kc], acc[rf][cf]);
    cur = nxt;
  }
  // epilogue
#pragma unroll
  for (int rf=0;rf<4;rf++){
#pragma unroll
    for (int cf=0;cf<4;cf++){
#pragma unroll
      for (int r=0;r<4;r++){
        int m = m0 + wm*64 + rf*16 + hi*4 + r;
        int n = n0 + wn*64 + cf*16 + lo;
        if (n < Nvalid){
          float v = acc[rf][cf][r];
          size_t idx = (size_t)m*ldc + n;
          if (MODE == 1){
            ((float*)Cv)[idx] = v;
          } else if (MODE == 0){
            ((ushort_t*)Cv)[idx] = f2bf(v);
          } else {
            float g = bf2f(((ushort_t*)Cv)[idx]);
            float ga = 0.5f*g*(1.f + tanhf(0.7978845608028654f*(g + 0.044715f*g*g*g)));
            ((ushort_t*)Cv)[idx] = f2bf(ga * v);
          }
        }
      }
    }
  }
}

// ---------------- RoPE ----------------
__global__ void rope_tab_kernel(float* __restrict__ tab){
  int s = blockIdx.x, i = threadIdx.x;             // s<1024, i<64
  float invf = __expf(-(float)i * (9.210340371976184f/64.f));  // 10000^(-i/64)
  float ph = (float)s * invf;
  float sn, cs;
  sincosf(ph, &sn, &cs);
  tab[s*128 + i] = cs;
  tab[s*128 + 64 + i] = sn;
}

__global__ __launch_bounds__(256) void rope_apply(ushort_t* __restrict__ qkv,
                                                  const float* __restrict__ tab){
  int idx = blockIdx.x*256 + threadIdx.x;          // 2048*40*64 total
  int pr = idx & 63;
  int h  = (idx >> 6) % 40;                        // 32 q heads + 8 k heads
  int row = idx / 2560;
  int t = row & (SEQ-1);
  ushort_t* p = qkv + (size_t)row*QKV_N + h*HD + pr;
  float c = tab[t*128 + pr], s = tab[t*128 + 64 + pr];
  float x1 = bf2f(p[0]), x2 = bf2f(p[64]);
  p[0]  = f2bf(x1*c - x2*s);
  p[64] = f2bf(x2*c + x1*s);
}

// ---------------- V transpose: VT[d][m] = qkv[m][5120+d] ----------------
__global__ __launch_bounds__(256) void transpose_v(const ushort_t* __restrict__ qkv,
                                                   ushort_t* __restrict__ VT){
  __shared__ ushort_t tile[32][33];
  int d0 = blockIdx.x*32, m0 = blockIdx.y*32;
  int tx = threadIdx.x & 31, ty = threadIdx.x >> 5;
#pragma unroll
  for (int i=0;i<4;i++)
    tile[ty + i*8][tx] = qkv[(size_t)(m0 + ty + i*8)*QKV_N + 5120 + d0 + tx];
  __syncthreads();
#pragma unroll
  for (int i=0;i<4;i++)
    VT[(size_t)(d0 + ty + i*8)*BROWS + m0 + tx] = tile[tx][ty + i*8];
}

// ---------------- Flash attention with tanh soft-cap, GQA, causal ----------------
__global__ __launch_bounds__(256) void attn_kernel(const ushort_t* __restrict__ qkv,
                                                   const ushort_t* __restrict__ VT,
                                                   ushort_t* __restrict__ outp){
  const int blk = blockIdx.x;
  const int bh = blk & 63;
  const int tgrp = 15 - (blk >> 6);     // heavy tiles dispatched first
  const int b = bh >> 5, qh = bh & 31, kv = qh >> 2;
  const int w = threadIdx.x >> 6, lane = threadIdx.x & 63;
  const int lo = lane & 15, hi = lane >> 4;
  const int t0 = tgrp*64 + w*16;
  __shared__ ushort_t P[4][16][72];     // per-wave P transpose buffer
  ushort_t (*Pw)[72] = P[w];

  const ushort_t* Qb = qkv + (size_t)(b*SEQ + t0 + lo)*QKV_N + qh*HD + hi*8;
  bf16x8 qf[4];
#pragma unroll
  for (int c=0;c<4;c++) qf[c] = ldb8(Qb + c*32);

  f32x4 of[8];
#pragma unroll
  for (int i=0;i<8;i++) of[i] = zero4();
  float ls[4] = {0.f,0.f,0.f,0.f};

  const ushort_t* Kb = qkv + (size_t)(b*SEQ + lo)*QKV_N + D_MODEL + kv*HD + hi*8;
  const ushort_t* Vb = VT + (size_t)(kv*HD + lo)*BROWS + b*SEQ + hi*8;

  const int nst = tgrp + 1;
  for (int st=0; st<nst; st++){
    const int s0 = st*64;
    f32x4 sacc[4];
#pragma unroll
    for (int nf=0;nf<4;nf++) sacc[nf] = zero4();
#pragma unroll
    for (int c=0;c<4;c++){
#pragma unroll
      for (int nf=0;nf<4;nf++){
        bf16x8 kf = ldb8(Kb + (size_t)(s0 + nf*16)*QKV_N + c*32);
        sacc[nf] = MFMA(qf[c], kf, sacc[nf]);
      }
    }
    // softmax (fixed max = 30 thanks to tanh cap) + write P^T to LDS
#pragma unroll
    for (int nf=0;nf<4;nf++){
#pragma unroll
      for (int r=0;r<4;r++){
        int tq = t0 + hi*4 + r;
        int s = s0 + nf*16 + lo;
        float xx = sacc[nf][r] * ATTN_MULT;
        float z = fminf(fmaxf(xx*(2.f/30.f), -80.f), 80.f);
        float e = __expf(z);
        float th = (e - 1.f)/(e + 1.f);
        float p = (s <= tq) ? __expf(30.f*th - 30.f) : 0.f;
        ls[r] += p;
        Pw[hi*4+r][nf*16+lo] = f2bf(p);
      }
    }
    __builtin_amdgcn_sched_barrier(0);
    __builtin_amdgcn_s_waitcnt(0xc07f);   // lgkmcnt(0): P writes visible wave-wide
    __builtin_amdgcn_sched_barrier(0);
#pragma unroll
    for (int c2=0;c2<2;c2++){
      bf16x8 pf = ldb8(&Pw[lo][c2*32 + hi*8]);
#pragma unroll
      for (int nf2=0;nf2<8;nf2++){
        bf16x8 vf = ldb8(Vb + (size_t)(nf2*16)*BROWS + s0 + c2*32);
        of[nf2] = MFMA(pf, vf, of[nf2]);
      }
    }
    __builtin_amdgcn_sched_barrier(0);
  }
#pragma unroll
  for (int m=1;m<16;m<<=1){
#pragma unroll
    for (int r=0;r<4;r++) ls[r] += __shfl_xor(ls[r], m);
  }
  float inv[4];
#pragma unroll
  for (int r=0;r<4;r++) inv[r] = 1.f/ls[r];
  ushort_t* Ob = outp + (size_t)(b*SEQ + t0 + hi*4)*D_MODEL + qh*HD + lo;
#pragma unroll
  for (int nf2=0;nf2<8;nf2++)
#pragma unroll
    for (int r=0;r<4;r++)
      Ob[(size_t)r*D_MODEL + nf2*16] = f2bf(of[nf2][r]*inv[r]);
}

// =============================== host launcher ===============================
extern "C" void kernel_launch(void* const* d_in, const int* in_sizes, int n_in,
                              void* d_out, int out_size, void* d_ws, size_t ws_size,
                              hipStream_t stream){
  const float* x        = (const float*)d_in[0];
  const float* sc_pre_a = (const float*)d_in[2];
  const float* sc_post_a= (const float*)d_in[3];
  const float* sc_pre_m = (const float*)d_in[4];
  const float* sc_post_m= (const float*)d_in[5];
  const float* wq  = (const float*)d_in[6];
  const float* wk  = (const float*)d_in[7];
  const float* wv  = (const float*)d_in[8];
  const float* wo  = (const float*)d_in[9];
  const float* wg  = (const float*)d_in[10];
  const float* wva = (const float*)d_in[11];
  const float* wou = (const float*)d_in[12];

  char* ws = (char*)d_ws;
  size_t off = 0;
  auto alloc = [&](size_t bytes)->void*{
    void* p = ws + off; off += (bytes + 255) & ~(size_t)255; return p;
  };
  ushort_t* WT   = (ushort_t*)alloc((size_t)FFN_GRID*D_MODEL*2); // reusable weight slot
  ushort_t* hn   = (ushort_t*)alloc((size_t)BROWS*D_MODEL*2);
  ushort_t* qkv  = (ushort_t*)alloc((size_t)BROWS*QKV_N*2);
  ushort_t* VT   = (ushort_t*)alloc((size_t)SEQ*BROWS*2);
  ushort_t* attn = (ushort_t*)alloc((size_t)BROWS*D_MODEL*2);
  float*    tmp32= (float*)alloc((size_t)BROWS*D_MODEL*4);
  ushort_t* hn2  = (ushort_t*)alloc((size_t)BROWS*D_MODEL*2);
  ushort_t* act  = (ushort_t*)alloc((size_t)BROWS*FFN_PAD*2);
  float*    rtab = (float*)alloc((size_t)SEQ*128*4);
  float* h = (float*)d_out;

  // 1. pre-attn norm
  rmsnorm_in<<<BROWS, 256, 0, stream>>>(x, sc_pre_a, hn);
  // 2. convert wq|wk|wv -> WT[6144][4096]
  convT<<<dim3(4096/32, 4096/64), 256, 0, stream>>>(wq, WT,                     4096, 4096, 4096, 4096);
  convT<<<dim3(1024/32, 4096/64), 256, 0, stream>>>(wk, WT + (size_t)4096*4096, 4096, 1024, 4096, 1024);
  convT<<<dim3(1024/32, 4096/64), 256, 0, stream>>>(wv, WT + (size_t)5120*4096, 4096, 1024, 4096, 1024);
  // 3. fused QKV GEMM (8 m x 48 n = 384 blocks)
  gemm256<0><<<384, 512, 0, stream>>>(hn, 4096, WT, 4096, qkv, QKV_N, QKV_N, 4096);
  // 4. RoPE on q,k
  rope_tab_kernel<<<SEQ, 64, 0, stream>>>(rtab);
  rope_apply<<<(BROWS*40*64)/256, 256, 0, stream>>>(qkv, rtab);
  // 5. V transpose for PV B-operand
  transpose_v<<<dim3(32,64), 256, 0, stream>>>(qkv, VT);
  // 6. attention
  attn_kernel<<<1024, 256, 0, stream>>>(qkv, VT, attn);
  // 7-8. O projection (8 x 32 = 256 blocks, 100% fill)
  convT<<<dim3(4096/32, 4096/64), 256, 0, stream>>>(wo, WT, 4096, 4096, 4096, 4096);
  gemm256<1><<<256, 512, 0, stream>>>(attn, 4096, WT, 4096, tmp32, 4096, 4096, 4096);
  // 9. h = x + rms(o)*sc ; hn2 = rms(h)*sc_pre_mlp
  rmsnorm_resid<<<BROWS, 256, 0, stream>>>(x, tmp32, sc_post_a, h, sc_pre_m, hn2);
  // 10-11. gate GEMM (8 x 86 = 688 blocks)
  convT<<<dim3(FFN_GRID/32, 4096/64), 256, 0, stream>>>(wg, WT, 4096, 10928, 4096, FFN_GRID);
  gemm256<0><<<688, 512, 0, stream>>>(hn2, 4096, WT, 4096, act, FFN_PAD, FFN_PAD, 4096);
  // 12-13. val GEMM fused with act = gelu(gate)*val
  convT<<<dim3(FFN_GRID/32, 4096/64), 256, 0, stream>>>(wva, WT, 4096, 10928, 4096, FFN_GRID);
  gemm256<2><<<688, 512, 0, stream>>>(hn2, 4096, WT, 4096, act, FFN_PAD, FFN_PAD, 4096);
  // 14-15. out projection (K padded 10928->10944 with zeros; 256 blocks, 100% fill)
  convT<<<dim3(4096/32, FFN_PAD/64), 256, 0, stream>>>(wou, WT, 10928, 4096, FFN_PAD, 4096);
  gemm256<1><<<256, 512, 0, stream>>>(act, FFN_PAD, WT, FFN_PAD, tmp32, 4096, 4096, FFN_PAD);
  // 16. final residual + norm (in-place on d_out)
  rmsnorm_resid<<<BROWS, 256, 0, stream>>>(h, tmp32, sc_post_m, h, nullptr, nullptr);
}